// Round 11
// baseline (160.196 us; speedup 1.0000x reference)
//
#include <hip/hip_runtime.h>
#include <hip/hip_bf16.h>

#define SS 2048
#define DD 512
#define HWIN 128

typedef __bf16 bf16x8 __attribute__((ext_vector_type(8)));
typedef unsigned short u16x8 __attribute__((ext_vector_type(8)));
typedef float f32x4 __attribute__((ext_vector_type(4)));

__device__ __forceinline__ unsigned short f2bf(float x) {
    unsigned u = __builtin_bit_cast(unsigned, x);
    return (unsigned short)((u + 0x7fffu + ((u >> 16) & 1u)) >> 16);
}
__device__ __forceinline__ float bf2f(unsigned short s) {
    unsigned u = ((unsigned)s) << 16;
    return __builtin_bit_cast(float, u);
}
__device__ __forceinline__ void split_bf(float x, unsigned short& h, unsigned short& l) {
    h = f2bf(x);
    l = f2bf(x - bf2f(h));
}
__device__ __forceinline__ u16x8 cvt8(float4 f0, float4 f1) {
    const float vals[8] = {f0.x, f0.y, f0.z, f0.w, f1.x, f1.y, f1.z, f1.w};
    u16x8 h;
    #pragma unroll
    for (int i = 0; i < 8; ++i) h[i] = f2bf(vals[i]);
    return h;
}
__device__ __forceinline__ f32x4 mfma16(u16x8 a, u16x8 b, f32x4 c) {
    return __builtin_amdgcn_mfma_f32_16x16x32_bf16(
        __builtin_bit_cast(bf16x8, a), __builtin_bit_cast(bf16x8, b), c, 0, 0, 0);
}
// Direct global -> LDS DMA, 16 B per lane (dest = wave-uniform base + lane*16).
__device__ __forceinline__ void gload16(const unsigned short* g, unsigned short* l) {
    __builtin_amdgcn_global_load_lds(
        (const __attribute__((address_space(1))) unsigned int*)g,
        (__attribute__((address_space(3))) unsigned int*)l, 16, 0, 0);
}

// ---------------------------------------------------------------------------
// Wo -> WoP (paired hi/lo) only.  All other casts are fused in-register into
// proj_gemm's staging (R11): the bf16 bits produced there are identical
// (same f2bf), and the A/W fp32->bf16 VALU rides free under staging latency
// (R0/R1 evidence).  262144 elems -> 128 blocks, ~1.3 us.
// ---------------------------------------------------------------------------
__global__ __launch_bounds__(256) void castWo(
    const float* __restrict__ wo, unsigned short* __restrict__ WoP)
{
    const size_t e0 = ((size_t)blockIdx.x * 256 + threadIdx.x) * 8;
    const float4 f0 = *(const float4*)(wo + e0), f1 = *(const float4*)(wo + e0 + 4);
    const float vals[8] = {f0.x, f0.y, f0.z, f0.w, f1.x, f1.y, f1.z, f1.w};
    u16x8 h, l;
    #pragma unroll
    for (int i = 0; i < 8; ++i) {
        unsigned short hh, ll;
        split_bf(vals[i], hh, ll);
        h[i] = hh; l[i] = ll;
    }
    *(u16x8*)(WoP + 2 * e0)     = h;
    *(u16x8*)(WoP + 2 * e0 + 8) = l;
}

// ---------------------------------------------------------------------------
// proj GEMM (128x64 tile, BK=32, grid 768): C = A@W.T + bias.
// FUSED-CAST round: A and W are read as fp32 and converted in-register
// (f2bf, single product) during staging — castAll deleted; net HBM -29 MB.
// R1 2-barrier single-buffer structure.  LDS 12 KiB.
// z<2: write OH hi.  z==2: write VTH hi + DETERMINISTIC V column partials:
// csum per wave -> shfl over lq -> part[(y*2+wm)*512+col] plain store
// (no atomics, no zeroed buffer needed; attn sums the 32 partials).
// Q/K/V bf16 outputs are bit-identical to R10.
// ---------------------------------------------------------------------------
__global__ __launch_bounds__(256) void proj_gemm(
    const float* __restrict__ q, const float* __restrict__ k, const float* __restrict__ v,
    const float* __restrict__ wq, const float* __restrict__ wk, const float* __restrict__ wv,
    const float* __restrict__ bq, const float* __restrict__ bk, const float* __restrict__ bv,
    unsigned short* __restrict__ base,
    unsigned short* __restrict__ VTH, float* __restrict__ part)
{
    const int d = blockIdx.x;              // 0..767
    const int hi = d >> 6, low = d & 63;
    const int x = low >> 3, rsw = low & 7;
    const int g = hi * 8 + rsw;            // 0..95
    const int y = g / 3, z = g - y * 3;    // y 0..31

    const float* Ap = (z == 0) ? q : ((z == 1) ? k : v);
    const float* Wp = (z == 0) ? wq : ((z == 1) ? wk : wv);
    const float* bias = (z == 0) ? bq : ((z == 1) ? bk : bv);
    unsigned short* OH = base + (size_t)z * 4194304;

    const int m0 = y * 128, n0 = x * 64;

    __shared__ unsigned short Ah[8 * 64 * 8];   // 8 KiB
    __shared__ unsigned short Bh[4 * 64 * 8];   // 4 KiB

    const int tid = threadIdx.x, wave = tid >> 6, lane = tid & 63;
    const int lm = lane & 15, lq = lane >> 4;
    const int wm = wave >> 1, wn = wave & 1;
    const int kb = lq * 8;

    f32x4 acc[4][2] = {};

    const int ar0 = m0 + (wave * 2 + 0) * 16 + lm;
    const int ar1 = m0 + (wave * 2 + 1) * 16 + lm;
    const int br  = n0 + wave * 16 + lm;

    const int aoff0 = ((wave * 2 + 0) * 64 + lane) * 8;
    const int aoff1 = ((wave * 2 + 1) * 64 + lane) * 8;
    const int boff  = (wave * 64 + lane) * 8;

    for (int k0 = 0; k0 < 512; k0 += 32) {
        // fp32 loads issued before the barrier (latency overlapped)
        const float* pa0 = Ap + (size_t)ar0 * 512 + k0 + kb;
        const float* pa1 = Ap + (size_t)ar1 * 512 + k0 + kb;
        const float* pw  = Wp + (size_t)br  * 512 + k0 + kb;
        const float4 a00 = *(const float4*)pa0, a01 = *(const float4*)(pa0 + 4);
        const float4 a10 = *(const float4*)pa1, a11 = *(const float4*)(pa1 + 4);
        const float4 w0  = *(const float4*)pw,  w1  = *(const float4*)(pw + 4);

        __syncthreads();                 // prev iteration's frag reads done
        *(u16x8*)&Ah[aoff0] = cvt8(a00, a01);
        *(u16x8*)&Ah[aoff1] = cvt8(a10, a11);
        *(u16x8*)&Bh[boff]  = cvt8(w0, w1);
        __syncthreads();                 // staging visible

        u16x8 afh[4], bfh[2];
        #pragma unroll
        for (int i = 0; i < 4; ++i)
            afh[i] = *(const u16x8*)&Ah[((wm * 4 + i) * 64 + lane) * 8];
        #pragma unroll
        for (int j = 0; j < 2; ++j)
            bfh[j] = *(const u16x8*)&Bh[((wn * 2 + j) * 64 + lane) * 8];
        #pragma unroll
        for (int i = 0; i < 4; ++i)
            #pragma unroll
            for (int j = 0; j < 2; ++j)
                acc[i][j] = mfma16(afh[i], bfh[j], acc[i][j]);
    }

    if (z < 2) {
        #pragma unroll
        for (int i = 0; i < 4; ++i)
            #pragma unroll
            for (int j = 0; j < 2; ++j) {
                const int col = n0 + (wn * 2 + j) * 16 + lm;
                const float bv_ = bias[col];
                #pragma unroll
                for (int r = 0; r < 4; ++r) {
                    const int row = m0 + (wm * 4 + i) * 16 + lq * 4 + r;
                    OH[(size_t)row * 512 + col] = f2bf(acc[i][j][r] + bv_);
                }
            }
    } else {
        // epilogue: VTH hi write + deterministic column partials
        float csum[2] = {0.f, 0.f};
        #pragma unroll
        for (int i = 0; i < 4; ++i)
            #pragma unroll
            for (int j = 0; j < 2; ++j) {
                const int col = n0 + (wn * 2 + j) * 16 + lm;
                const float bv_ = bias[col];
                #pragma unroll
                for (int r = 0; r < 4; ++r) {
                    const int row = m0 + (wm * 4 + i) * 16 + lq * 4 + r;
                    const float vv = acc[i][j][r] + bv_;
                    csum[j] += vv;
                    const size_t vix =
                        (((size_t)(row >> 11) * 8 + (col >> 6)) * 64 + (col & 63)) * 2048
                        + (row & 2047);
                    VTH[vix] = f2bf(vv);
                }
            }
        // reduce over lq; wave (wm) owns rowblock y*2+wm (64 rows), store once
        #pragma unroll
        for (int j = 0; j < 2; ++j) {
            float s = csum[j];
            s += __shfl_xor(s, 16);
            s += __shfl_xor(s, 32);
            if (lq == 0) {
                const int col = n0 + (wn * 2 + j) * 16 + lm;
                part[(size_t)(y * 2 + wm) * 512 + col] = s;
            }
        }
    }
}

// ---------------------------------------------------------------------------
// out GEMM, BK=64: 64x64 tile, grid 512.  Pure-DMA 2-phase pipeline,
// split-bf16 kept (final dot gets the insurance).  Unchanged.
// ---------------------------------------------------------------------------
__global__ __launch_bounds__(256) void out_gemm(
    const unsigned short* __restrict__ XHg, const unsigned short* __restrict__ XLg,
    const unsigned short* __restrict__ WoP, const float* __restrict__ bo,
    float* __restrict__ O)
{
    const int gid = blockIdx.x;            // 0..511
    const int rr = gid & 7, hi = gid >> 3;
    const int nblk = hi & 7, mhi = hi >> 3;
    const int mblk = mhi * 8 + rr;         // 0..63
    const int m0 = mblk * 64, n0 = nblk * 64;

    __shared__ unsigned short Ah[2 * 4096], Al[2 * 4096];
    __shared__ unsigned short Bh[2 * 4096], Bl[2 * 4096];

    const int tid = threadIdx.x, wave = tid >> 6, lane = tid & 63;
    const int lm = lane & 15, lq = lane >> 4;
    const int kb = lq * 8;

    f32x4 acc[4] = {};

    const int arow = m0 + wave * 16 + lm;
    const int brow = n0 + wave * 16 + lm;

    #define OSTAGE(k0_, bs)                                                     \
    {                                                                           \
        _Pragma("unroll")                                                       \
        for (int s = 0; s < 2; ++s) {                                           \
            const int o = (bs) * 4096 + ((s * 4 + wave) * 64 + lane) * 8;       \
            gload16(XHg + (size_t)arow * 512 + (k0_) + s * 32 + kb, &Ah[o]);    \
            gload16(XLg + (size_t)arow * 512 + (k0_) + s * 32 + kb, &Al[o]);    \
            const unsigned short* pw =                                          \
                WoP + 2 * ((size_t)brow * 512 + (k0_) + s * 32 + kb);           \
            gload16(pw,     &Bh[o]);                                            \
            gload16(pw + 8, &Bl[o]);                                            \
        }                                                                       \
    }

    OSTAGE(0, 0);
    __syncthreads();

    for (int t = 0; t < 8; ++t) {
        const int cur = t & 1;
        if (t < 7) OSTAGE((t + 1) * 64, cur ^ 1);

        #pragma unroll
        for (int s = 0; s < 2; ++s) {
            const u16x8 a_h = *(const u16x8*)&Ah[cur * 4096 + ((s * 4 + wave) * 64 + lane) * 8];
            const u16x8 a_l = *(const u16x8*)&Al[cur * 4096 + ((s * 4 + wave) * 64 + lane) * 8];
            #pragma unroll
            for (int j = 0; j < 4; ++j) {
                const u16x8 b_h = *(const u16x8*)&Bh[cur * 4096 + ((s * 4 + j) * 64 + lane) * 8];
                const u16x8 b_l = *(const u16x8*)&Bl[cur * 4096 + ((s * 4 + j) * 64 + lane) * 8];
                acc[j] = mfma16(a_h, b_h, acc[j]);
                acc[j] = mfma16(a_h, b_l, acc[j]);
                acc[j] = mfma16(a_l, b_h, acc[j]);
            }
        }

        __syncthreads();
    }
    #undef OSTAGE

    #pragma unroll
    for (int j = 0; j < 4; ++j) {
        const int col = n0 + j * 16 + lm;
        const float bv_ = bo[col];
        #pragma unroll
        for (int r = 0; r < 4; ++r) {
            const int row = m0 + wave * 16 + lq * 4 + r;
            O[(size_t)row * 512 + col] = acc[j][r] + bv_;
        }
    }
}

// ---------------------------------------------------------------------------
// PLAIN-bf16 MFMA sliding-window attention.  R5 barrier-diet + R10
// masked-subtile skip.  R11: VS is reconstructed in the epilogue from the
// 32 deterministic rowblock partials written by proj (fixed order, no
// atomics).  Everything else unchanged.
//   x = [ sum_win (e^s - 1) v + VS ] / ( 2048 + sum_win (e^s - 1) )
// ---------------------------------------------------------------------------
__global__ __launch_bounds__(256) void attn_mfma(
    const unsigned short* __restrict__ QH, const unsigned short* __restrict__ KH,
    const unsigned short* __restrict__ VTH, const float* __restrict__ part,
    unsigned short* __restrict__ XH, unsigned short* __restrict__ XL)
{
    const int dblk = blockIdx.x;
    const int bhi = dblk >> 8, blow = dblk & 255;
    const int xblk = blow >> 3, rrs = blow & 7;
    const int bh = bhi * 8 + rrs;        // 0..15
    const int h = bh & 7, b = bh >> 3;
    const int i0 = xblk * 64;
    const int tid = threadIdx.x, wave = tid >> 6, lane = tid & 63;
    const int lm = lane & 15, lq = lane >> 4;
    const int kb = lq * 8;

    __shared__ unsigned short KfH[2 * 8 * 64 * 8];   // [buf][js*2+c][lane][8]
    __shared__ unsigned short VfH[2 * 8 * 64 * 8];   // [buf][s4*2+c][lane][8]
    __shared__ unsigned short Swh[64][72];           // [q][j], wave-private rows

    const size_t qoff = ((size_t)(b * SS + i0 + wave * 16 + lm)) * DD + h * 64 + kb;
    const u16x8 aQ0h = *(const u16x8*)(QH + qoff);
    const u16x8 aQ1h = *(const u16x8*)(QH + qoff + 32);

    f32x4 oacc[4] = {};
    float dacc[4] = {0.f, 0.f, 0.f, 0.f};

    const size_t vrow = ((size_t)bh * 64 + wave * 16 + lm) * 2048;
    const int s0 = (wave * 2 + 0) * 64 * 8 + lane * 8;   // this wave's slot bases
    const int s1 = (wave * 2 + 1) * 64 * 8 + lane * 8;

    // stage K/V tile jt_ into buffer bufsel
    #define STAGE(jt_, bufsel)                                                  \
    {                                                                           \
        const int jt0_ = i0 - 128 + (jt_) * 64;                                 \
        const int jrow = jt0_ + wave * 16 + lm;                                 \
        const int jrc = min(max(jrow, 0), SS - 1);                              \
        const size_t kgb = ((size_t)(b * SS + jrc)) * DD + h * 64 + kb;         \
        gload16(KH + kgb,      &KfH[(bufsel) * 4096 + s0]);                     \
        gload16(KH + kgb + 32, &KfH[(bufsel) * 4096 + s1]);                     \
        const int j0c = min(max(jt0_ + kb, 0), SS - 8);                         \
        const int j1c = min(max(jt0_ + 32 + kb, 0), SS - 8);                    \
        gload16(VTH + vrow + j0c, &VfH[(bufsel) * 4096 + s0]);                  \
        gload16(VTH + vrow + j1c, &VfH[(bufsel) * 4096 + s1]);                  \
    }

    STAGE(0, 0);
    __syncthreads();

    for (int jt = 0; jt < 5; ++jt) {
        const int buf = jt & 1;
        if (jt < 4) STAGE(jt + 1, buf ^ 1);   // in flight under this jt's compute
        const int jt0 = i0 - 128 + jt * 64;
        const int rmin = i0 + wave * 16;      // this wave's q rows [rmin, rmin+15]

        #pragma unroll
        for (int js = 0; js < 4; ++js) {
            const int j0 = js * 16;
            const int cmin = jt0 + j0, cmax = cmin + 15;
            // wave-uniform full-mask test: whole 16x16 subtile out of window/bounds
            const bool skip = (cmax < 0) || (cmin >= SS) ||
                              (cmax < rmin - HWIN) || (cmin > rmin + 15 + HWIN);
            if (skip) {
                #pragma unroll
                for (int r = 0; r < 4; ++r)
                    Swh[wave * 16 + lq * 4 + r][j0 + lm] = 0;   // == f2bf(0.0f)
                continue;
            }
            const u16x8 bK0h = *(const u16x8*)&KfH[buf * 4096 + ((js * 2 + 0) * 64 + lane) * 8];
            const u16x8 bK1h = *(const u16x8*)&KfH[buf * 4096 + ((js * 2 + 1) * 64 + lane) * 8];
            f32x4 s = {0.f, 0.f, 0.f, 0.f};
            s = mfma16(aQ0h, bK0h, s);
            s = mfma16(aQ1h, bK1h, s);
            const int jg = jt0 + j0 + lm;
            const int iq = i0 + wave * 16 + lq * 4;
            #pragma unroll
            for (int r = 0; r < 4; ++r) {
                const int qi = iq + r;
                const bool in = (jg >= 0) && (jg < SS) &&
                                (jg >= qi - HWIN) && (jg <= qi + HWIN);
                const float w = in ? (__expf(s[r] * 0.125f) - 1.0f) : 0.0f;
                dacc[r] += w;
                Swh[wave * 16 + lq * 4 + r][j0 + lm] = f2bf(w);
            }
        }

        // no barrier: Swh rows are wave-private (write/read by same wave)
        const u16x8 aP0h = *(const u16x8*)&Swh[wave * 16 + lm][kb];
        const u16x8 aP1h = *(const u16x8*)&Swh[wave * 16 + lm][kb + 32];
        #pragma unroll
        for (int s4 = 0; s4 < 4; ++s4) {
            const u16x8 bV0h = *(const u16x8*)&VfH[buf * 4096 + ((s4 * 2 + 0) * 64 + lane) * 8];
            const u16x8 bV1h = *(const u16x8*)&VfH[buf * 4096 + ((s4 * 2 + 1) * 64 + lane) * 8];
            oacc[s4] = mfma16(aP0h, bV0h, oacc[s4]);
            oacc[s4] = mfma16(aP1h, bV1h, oacc[s4]);
        }
        __syncthreads();   // next buf staged + this buf's reads done
    }
    #undef STAGE

    #pragma unroll
    for (int r = 0; r < 4; ++r) {
        float v = dacc[r];
        v += __shfl_xor(v, 1);
        v += __shfl_xor(v, 2);
        v += __shfl_xor(v, 4);
        v += __shfl_xor(v, 8);
        dacc[r] = v + 2048.0f;
    }

    #pragma unroll
    for (int s4 = 0; s4 < 4; ++s4) {
        // VS = fixed-order sum of the 32 rowblock partials for this (b,col)
        const float* pp = part + (size_t)(b * 32) * 512 + h * 64 + s4 * 16 + lm;
        float vsv = 0.f;
        #pragma unroll 8
        for (int p = 0; p < 32; ++p) vsv += pp[(size_t)p * 512];
        #pragma unroll
        for (int r = 0; r < 4; ++r) {
            const int qrow = i0 + wave * 16 + lq * 4 + r;
            const float x = (oacc[s4][r] + vsv) / dacc[r];
            unsigned short xh, xl;
            split_bf(x, xh, xl);
            const size_t ix = ((size_t)(b * SS + qrow)) * DD + h * 64 + s4 * 16 + lm;
            XH[ix] = xh;
            XL[ix] = xl;
        }
    }
}

// ---------------------------------------------------------------------------
extern "C" void kernel_launch(void* const* d_in, const int* in_sizes, int n_in,
                              void* d_out, int out_size, void* d_ws, size_t ws_size,
                              hipStream_t stream)
{
    const float* query  = (const float*)d_in[0];
    const float* key_in = (const float*)d_in[1];
    const float* value  = (const float*)d_in[2];
    const float* Wq = (const float*)d_in[3]; const float* bq = (const float*)d_in[4];
    const float* Wk = (const float*)d_in[5]; const float* bk = (const float*)d_in[6];
    const float* Wv = (const float*)d_in[7]; const float* bv = (const float*)d_in[8];
    const float* Wo = (const float*)d_in[9]; const float* bo = (const float*)d_in[10];

    unsigned short* wsb = (unsigned short*)d_ws;
    unsigned short* QH  = wsb;                 // z=0 output (hi only)
    unsigned short* KH  = wsb + 4194304;       // z=1 output (hi only)
    unsigned short* VTH = wsb + 8388608;       // V transposed hi [bh][d][s]
    unsigned short* XH  = wsb + 12582912;
    unsigned short* XL  = wsb + 14680064;
    unsigned short* WoP = wsb + 16777216;      // Wo paired (524288 shorts)
    float* partp = (float*)((char*)d_ws + 63045632);   // 64x512 V partials

    castWo<<<128, 256, 0, stream>>>(Wo, WoP);

    proj_gemm<<<768, 256, 0, stream>>>(query, key_in, value, Wq, Wk, Wv,
                                       bq, bk, bv, QH, VTH, partp);

    attn_mfma<<<512, 256, 0, stream>>>(QH, KH, VTH, partp, XH, XL);

    out_gemm<<<512, 256, 0, stream>>>(XH, XL, WoP, bo, (float*)d_out);
}

// Round 12
// 147.128 us; speedup vs baseline: 1.0888x; 1.0888x over previous
//
#include <hip/hip_runtime.h>
#include <hip/hip_bf16.h>

#define SS 2048
#define DD 512
#define HWIN 128

typedef __bf16 bf16x8 __attribute__((ext_vector_type(8)));
typedef unsigned short u16x8 __attribute__((ext_vector_type(8)));
typedef float f32x4 __attribute__((ext_vector_type(4)));

__device__ __forceinline__ unsigned short f2bf(float x) {
    unsigned u = __builtin_bit_cast(unsigned, x);
    return (unsigned short)((u + 0x7fffu + ((u >> 16) & 1u)) >> 16);
}
__device__ __forceinline__ float bf2f(unsigned short s) {
    unsigned u = ((unsigned)s) << 16;
    return __builtin_bit_cast(float, u);
}
__device__ __forceinline__ void split_bf(float x, unsigned short& h, unsigned short& l) {
    h = f2bf(x);
    l = f2bf(x - bf2f(h));
}
__device__ __forceinline__ f32x4 mfma16(u16x8 a, u16x8 b, f32x4 c) {
    return __builtin_amdgcn_mfma_f32_16x16x32_bf16(
        __builtin_bit_cast(bf16x8, a), __builtin_bit_cast(bf16x8, b), c, 0, 0, 0);
}
// Direct global -> LDS DMA, 16 B per lane (dest = wave-uniform base + lane*16).
__device__ __forceinline__ void gload16(const unsigned short* g, unsigned short* l) {
    __builtin_amdgcn_global_load_lds(
        (const __attribute__((address_space(1))) unsigned int*)g,
        (__attribute__((address_space(3))) unsigned int*)l, 16, 0, 0);
}

// ---------------------------------------------------------------------------
// Cast everything once (R10 structure — R11 proved in-proj fused cast costs
// 2x: gload16 DMA staging beats register-staging+convert when MFMA/step is
// small).  q,k,v and Wq,Wk,Wv PLAIN-HI bf16; Wo paired hi/lo.
// ---------------------------------------------------------------------------
__global__ __launch_bounds__(256) void castAll(
    const float* __restrict__ q, const float* __restrict__ k, const float* __restrict__ v,
    const float* __restrict__ wq, const float* __restrict__ wk,
    const float* __restrict__ wv, const float* __restrict__ wo,
    unsigned short* __restrict__ QAh, unsigned short* __restrict__ KAh,
    unsigned short* __restrict__ VAh,
    unsigned short* __restrict__ WQh, unsigned short* __restrict__ WKh,
    unsigned short* __restrict__ WVh, unsigned short* __restrict__ WoP)
{
    const size_t e0 = ((size_t)blockIdx.x * 256 + threadIdx.x) * 8;
    const float* src; size_t off; unsigned short* dsth; bool paired = false;
    if      (e0 < 2097152) { src = q; off = e0;           dsth = QAh + off; }
    else if (e0 < 4194304) { src = k; off = e0 - 2097152; dsth = KAh + off; }
    else if (e0 < 6291456) { src = v; off = e0 - 4194304; dsth = VAh + off; }
    else {
        const size_t e = e0 - 6291456;
        if      (e < 262144) { src = wq; off = e;          dsth = WQh + off; }
        else if (e < 524288) { src = wk; off = e - 262144; dsth = WKh + off; }
        else if (e < 786432) { src = wv; off = e - 524288; dsth = WVh + off; }
        else { src = wo; off = e - 786432; dsth = WoP + 2 * (e - 786432); paired = true; }
    }
    const float4 f0 = *(const float4*)(src + off), f1 = *(const float4*)(src + off + 4);
    const float vals[8] = {f0.x, f0.y, f0.z, f0.w, f1.x, f1.y, f1.z, f1.w};
    u16x8 h;
    #pragma unroll
    for (int i = 0; i < 8; ++i) h[i] = f2bf(vals[i]);
    *(u16x8*)dsth = h;
    if (paired) {
        u16x8 l;
        #pragma unroll
        for (int i = 0; i < 8; ++i) l[i] = f2bf(vals[i] - bf2f(h[i]));
        *(u16x8*)(dsth + 8) = l;
    }
}

// ---------------------------------------------------------------------------
// proj GEMM (128x64 tile, BK=32, grid 768): C = A@W.T + bias.
// R10 pure-DMA uniform single-product (best measured: ~21us).  3 gloads +
// 8 MFMA per step; LDS 12 KiB.  z<2: OH hi.  z==2: VTH hi + DETERMINISTIC
// V column partials (R11 keeper): csum -> shfl over lq ->
// part[(y*2+wm)*512+col] plain store; attn sums the 32 partials.
// ---------------------------------------------------------------------------
__global__ __launch_bounds__(256) void proj_gemm(
    const unsigned short* __restrict__ QAh, const unsigned short* __restrict__ KAh,
    const unsigned short* __restrict__ VAh,
    const unsigned short* __restrict__ WQh, const unsigned short* __restrict__ WKh,
    const unsigned short* __restrict__ WVh,
    const float* __restrict__ bq, const float* __restrict__ bk, const float* __restrict__ bv,
    unsigned short* __restrict__ base,
    unsigned short* __restrict__ VTH, float* __restrict__ part)
{
    const int d = blockIdx.x;              // 0..767
    const int hi = d >> 6, low = d & 63;
    const int x = low >> 3, rsw = low & 7;
    const int g = hi * 8 + rsw;            // 0..95
    const int y = g / 3, z = g - y * 3;    // y 0..31

    const unsigned short* Ap = (z == 0) ? QAh : ((z == 1) ? KAh : VAh);
    const unsigned short* Wp = (z == 0) ? WQh : ((z == 1) ? WKh : WVh);
    const float* bias = (z == 0) ? bq : ((z == 1) ? bk : bv);
    unsigned short* OH = base + (size_t)z * 4194304;

    const int m0 = y * 128, n0 = x * 64;

    __shared__ unsigned short Ah[8 * 64 * 8];   // 8 KiB
    __shared__ unsigned short Bh[4 * 64 * 8];   // 4 KiB

    const int tid = threadIdx.x, wave = tid >> 6, lane = tid & 63;
    const int lm = lane & 15, lq = lane >> 4;
    const int wm = wave >> 1, wn = wave & 1;
    const int kb = lq * 8;

    f32x4 acc[4][2] = {};

    const int ar0 = m0 + (wave * 2 + 0) * 16 + lm;
    const int ar1 = m0 + (wave * 2 + 1) * 16 + lm;
    const int br  = n0 + wave * 16 + lm;

    const int aoff0 = ((wave * 2 + 0) * 64 + lane) * 8;
    const int aoff1 = ((wave * 2 + 1) * 64 + lane) * 8;
    const int boff  = (wave * 64 + lane) * 8;

    for (int k0 = 0; k0 < 512; k0 += 32) {
        __syncthreads();                 // prev iteration's frag reads done
        gload16(Ap + (size_t)ar0 * 512 + k0 + kb, &Ah[aoff0]);
        gload16(Ap + (size_t)ar1 * 512 + k0 + kb, &Ah[aoff1]);
        gload16(Wp + (size_t)br  * 512 + k0 + kb, &Bh[boff]);
        __syncthreads();                 // staging visible

        u16x8 afh[4], bfh[2];
        #pragma unroll
        for (int i = 0; i < 4; ++i)
            afh[i] = *(const u16x8*)&Ah[((wm * 4 + i) * 64 + lane) * 8];
        #pragma unroll
        for (int j = 0; j < 2; ++j)
            bfh[j] = *(const u16x8*)&Bh[((wn * 2 + j) * 64 + lane) * 8];
        #pragma unroll
        for (int i = 0; i < 4; ++i)
            #pragma unroll
            for (int j = 0; j < 2; ++j)
                acc[i][j] = mfma16(afh[i], bfh[j], acc[i][j]);
    }

    if (z < 2) {
        #pragma unroll
        for (int i = 0; i < 4; ++i)
            #pragma unroll
            for (int j = 0; j < 2; ++j) {
                const int col = n0 + (wn * 2 + j) * 16 + lm;
                const float bv_ = bias[col];
                #pragma unroll
                for (int r = 0; r < 4; ++r) {
                    const int row = m0 + (wm * 4 + i) * 16 + lq * 4 + r;
                    OH[(size_t)row * 512 + col] = f2bf(acc[i][j][r] + bv_);
                }
            }
    } else {
        // epilogue: VTH hi write + deterministic column partials
        float csum[2] = {0.f, 0.f};
        #pragma unroll
        for (int i = 0; i < 4; ++i)
            #pragma unroll
            for (int j = 0; j < 2; ++j) {
                const int col = n0 + (wn * 2 + j) * 16 + lm;
                const float bv_ = bias[col];
                #pragma unroll
                for (int r = 0; r < 4; ++r) {
                    const int row = m0 + (wm * 4 + i) * 16 + lq * 4 + r;
                    const float vv = acc[i][j][r] + bv_;
                    csum[j] += vv;
                    const size_t vix =
                        (((size_t)(row >> 11) * 8 + (col >> 6)) * 64 + (col & 63)) * 2048
                        + (row & 2047);
                    VTH[vix] = f2bf(vv);
                }
            }
        // reduce over lq; wave half (wm) owns rowblock y*2+wm (64 rows)
        #pragma unroll
        for (int j = 0; j < 2; ++j) {
            float s = csum[j];
            s += __shfl_xor(s, 16);
            s += __shfl_xor(s, 32);
            if (lq == 0) {
                const int col = n0 + (wn * 2 + j) * 16 + lm;
                part[(size_t)(y * 2 + wm) * 512 + col] = s;
            }
        }
    }
}

// ---------------------------------------------------------------------------
// out GEMM, BK=64: 64x64 tile, grid 512.  Pure-DMA 2-phase pipeline,
// split-bf16 kept (final dot gets the insurance).  Unchanged.
// ---------------------------------------------------------------------------
__global__ __launch_bounds__(256) void out_gemm(
    const unsigned short* __restrict__ XHg, const unsigned short* __restrict__ XLg,
    const unsigned short* __restrict__ WoP, const float* __restrict__ bo,
    float* __restrict__ O)
{
    const int gid = blockIdx.x;            // 0..511
    const int rr = gid & 7, hi = gid >> 3;
    const int nblk = hi & 7, mhi = hi >> 3;
    const int mblk = mhi * 8 + rr;         // 0..63
    const int m0 = mblk * 64, n0 = nblk * 64;

    __shared__ unsigned short Ah[2 * 4096], Al[2 * 4096];
    __shared__ unsigned short Bh[2 * 4096], Bl[2 * 4096];

    const int tid = threadIdx.x, wave = tid >> 6, lane = tid & 63;
    const int lm = lane & 15, lq = lane >> 4;
    const int kb = lq * 8;

    f32x4 acc[4] = {};

    const int arow = m0 + wave * 16 + lm;
    const int brow = n0 + wave * 16 + lm;

    #define OSTAGE(k0_, bs)                                                     \
    {                                                                           \
        _Pragma("unroll")                                                       \
        for (int s = 0; s < 2; ++s) {                                           \
            const int o = (bs) * 4096 + ((s * 4 + wave) * 64 + lane) * 8;       \
            gload16(XHg + (size_t)arow * 512 + (k0_) + s * 32 + kb, &Ah[o]);    \
            gload16(XLg + (size_t)arow * 512 + (k0_) + s * 32 + kb, &Al[o]);    \
            const unsigned short* pw =                                          \
                WoP + 2 * ((size_t)brow * 512 + (k0_) + s * 32 + kb);           \
            gload16(pw,     &Bh[o]);                                            \
            gload16(pw + 8, &Bl[o]);                                            \
        }                                                                       \
    }

    OSTAGE(0, 0);
    __syncthreads();

    for (int t = 0; t < 8; ++t) {
        const int cur = t & 1;
        if (t < 7) OSTAGE((t + 1) * 64, cur ^ 1);

        #pragma unroll
        for (int s = 0; s < 2; ++s) {
            const u16x8 a_h = *(const u16x8*)&Ah[cur * 4096 + ((s * 4 + wave) * 64 + lane) * 8];
            const u16x8 a_l = *(const u16x8*)&Al[cur * 4096 + ((s * 4 + wave) * 64 + lane) * 8];
            #pragma unroll
            for (int j = 0; j < 4; ++j) {
                const u16x8 b_h = *(const u16x8*)&Bh[cur * 4096 + ((s * 4 + j) * 64 + lane) * 8];
                const u16x8 b_l = *(const u16x8*)&Bl[cur * 4096 + ((s * 4 + j) * 64 + lane) * 8];
                acc[j] = mfma16(a_h, b_h, acc[j]);
                acc[j] = mfma16(a_h, b_l, acc[j]);
                acc[j] = mfma16(a_l, b_h, acc[j]);
            }
        }

        __syncthreads();
    }
    #undef OSTAGE

    #pragma unroll
    for (int j = 0; j < 4; ++j) {
        const int col = n0 + j * 16 + lm;
        const float bv_ = bo[col];
        #pragma unroll
        for (int r = 0; r < 4; ++r) {
            const int row = m0 + wave * 16 + lq * 4 + r;
            O[(size_t)row * 512 + col] = acc[j][r] + bv_;
        }
    }
}

// ---------------------------------------------------------------------------
// PLAIN-bf16 MFMA sliding-window attention.  R5 barrier-diet + R10
// masked-subtile skip + R11 deterministic VS-from-partials.  Mask uses the
// unsigned-range trick (2 compares, same truth table -> bit-identical).
//   x = [ sum_win (e^s - 1) v + VS ] / ( 2048 + sum_win (e^s - 1) )
// ---------------------------------------------------------------------------
__global__ __launch_bounds__(256) void attn_mfma(
    const unsigned short* __restrict__ QH, const unsigned short* __restrict__ KH,
    const unsigned short* __restrict__ VTH, const float* __restrict__ part,
    unsigned short* __restrict__ XH, unsigned short* __restrict__ XL)
{
    const int dblk = blockIdx.x;
    const int bhi = dblk >> 8, blow = dblk & 255;
    const int xblk = blow >> 3, rrs = blow & 7;
    const int bh = bhi * 8 + rrs;        // 0..15
    const int h = bh & 7, b = bh >> 3;
    const int i0 = xblk * 64;
    const int tid = threadIdx.x, wave = tid >> 6, lane = tid & 63;
    const int lm = lane & 15, lq = lane >> 4;
    const int kb = lq * 8;

    __shared__ unsigned short KfH[2 * 8 * 64 * 8];   // [buf][js*2+c][lane][8]
    __shared__ unsigned short VfH[2 * 8 * 64 * 8];   // [buf][s4*2+c][lane][8]
    __shared__ unsigned short Swh[64][72];           // [q][j], wave-private rows

    const size_t qoff = ((size_t)(b * SS + i0 + wave * 16 + lm)) * DD + h * 64 + kb;
    const u16x8 aQ0h = *(const u16x8*)(QH + qoff);
    const u16x8 aQ1h = *(const u16x8*)(QH + qoff + 32);

    f32x4 oacc[4] = {};
    float dacc[4] = {0.f, 0.f, 0.f, 0.f};

    const size_t vrow = ((size_t)bh * 64 + wave * 16 + lm) * 2048;
    const int s0 = (wave * 2 + 0) * 64 * 8 + lane * 8;   // this wave's slot bases
    const int s1 = (wave * 2 + 1) * 64 * 8 + lane * 8;

    // stage K/V tile jt_ into buffer bufsel
    #define STAGE(jt_, bufsel)                                                  \
    {                                                                           \
        const int jt0_ = i0 - 128 + (jt_) * 64;                                 \
        const int jrow = jt0_ + wave * 16 + lm;                                 \
        const int jrc = min(max(jrow, 0), SS - 1);                              \
        const size_t kgb = ((size_t)(b * SS + jrc)) * DD + h * 64 + kb;         \
        gload16(KH + kgb,      &KfH[(bufsel) * 4096 + s0]);                     \
        gload16(KH + kgb + 32, &KfH[(bufsel) * 4096 + s1]);                     \
        const int j0c = min(max(jt0_ + kb, 0), SS - 8);                         \
        const int j1c = min(max(jt0_ + 32 + kb, 0), SS - 8);                    \
        gload16(VTH + vrow + j0c, &VfH[(bufsel) * 4096 + s0]);                  \
        gload16(VTH + vrow + j1c, &VfH[(bufsel) * 4096 + s1]);                  \
    }

    STAGE(0, 0);
    __syncthreads();

    for (int jt = 0; jt < 5; ++jt) {
        const int buf = jt & 1;
        if (jt < 4) STAGE(jt + 1, buf ^ 1);   // in flight under this jt's compute
        const int jt0 = i0 - 128 + jt * 64;
        const int rmin = i0 + wave * 16;      // this wave's q rows [rmin, rmin+15]

        #pragma unroll
        for (int js = 0; js < 4; ++js) {
            const int j0 = js * 16;
            const int cmin = jt0 + j0, cmax = cmin + 15;
            // wave-uniform full-mask test: whole 16x16 subtile out of window/bounds
            const bool skip = (cmax < 0) || (cmin >= SS) ||
                              (cmax < rmin - HWIN) || (cmin > rmin + 15 + HWIN);
            if (skip) {
                #pragma unroll
                for (int r = 0; r < 4; ++r)
                    Swh[wave * 16 + lq * 4 + r][j0 + lm] = 0;   // == f2bf(0.0f)
                continue;
            }
            const u16x8 bK0h = *(const u16x8*)&KfH[buf * 4096 + ((js * 2 + 0) * 64 + lane) * 8];
            const u16x8 bK1h = *(const u16x8*)&KfH[buf * 4096 + ((js * 2 + 1) * 64 + lane) * 8];
            f32x4 s = {0.f, 0.f, 0.f, 0.f};
            s = mfma16(aQ0h, bK0h, s);
            s = mfma16(aQ1h, bK1h, s);
            const int jg = jt0 + j0 + lm;
            const int iq = i0 + wave * 16 + lq * 4;
            #pragma unroll
            for (int r = 0; r < 4; ++r) {
                const int qi = iq + r;
                // unsigned-range trick: same truth table, 2 compares
                const bool in = ((unsigned)jg < (unsigned)SS) &&
                                ((unsigned)(jg - qi + HWIN) <= (unsigned)(2 * HWIN));
                const float w = in ? (__expf(s[r] * 0.125f) - 1.0f) : 0.0f;
                dacc[r] += w;
                Swh[wave * 16 + lq * 4 + r][j0 + lm] = f2bf(w);
            }
        }

        // no barrier: Swh rows are wave-private (write/read by same wave)
        const u16x8 aP0h = *(const u16x8*)&Swh[wave * 16 + lm][kb];
        const u16x8 aP1h = *(const u16x8*)&Swh[wave * 16 + lm][kb + 32];
        #pragma unroll
        for (int s4 = 0; s4 < 4; ++s4) {
            const u16x8 bV0h = *(const u16x8*)&VfH[buf * 4096 + ((s4 * 2 + 0) * 64 + lane) * 8];
            const u16x8 bV1h = *(const u16x8*)&VfH[buf * 4096 + ((s4 * 2 + 1) * 64 + lane) * 8];
            oacc[s4] = mfma16(aP0h, bV0h, oacc[s4]);
            oacc[s4] = mfma16(aP1h, bV1h, oacc[s4]);
        }
        __syncthreads();   // next buf staged + this buf's reads done
    }
    #undef STAGE

    #pragma unroll
    for (int r = 0; r < 4; ++r) {
        float v = dacc[r];
        v += __shfl_xor(v, 1);
        v += __shfl_xor(v, 2);
        v += __shfl_xor(v, 4);
        v += __shfl_xor(v, 8);
        dacc[r] = v + 2048.0f;
    }

    #pragma unroll
    for (int s4 = 0; s4 < 4; ++s4) {
        // VS = fixed-order sum of the 32 rowblock partials for this (b,col)
        const float* pp = part + (size_t)(b * 32) * 512 + h * 64 + s4 * 16 + lm;
        float vsv = 0.f;
        #pragma unroll 8
        for (int p = 0; p < 32; ++p) vsv += pp[(size_t)p * 512];
        #pragma unroll
        for (int r = 0; r < 4; ++r) {
            const int qrow = i0 + wave * 16 + lq * 4 + r;
            const float x = (oacc[s4][r] + vsv) / dacc[r];
            unsigned short xh, xl;
            split_bf(x, xh, xl);
            const size_t ix = ((size_t)(b * SS + qrow)) * DD + h * 64 + s4 * 16 + lm;
            XH[ix] = xh;
            XL[ix] = xl;
        }
    }
}

// ---------------------------------------------------------------------------
extern "C" void kernel_launch(void* const* d_in, const int* in_sizes, int n_in,
                              void* d_out, int out_size, void* d_ws, size_t ws_size,
                              hipStream_t stream)
{
    const float* query  = (const float*)d_in[0];
    const float* key_in = (const float*)d_in[1];
    const float* value  = (const float*)d_in[2];
    const float* Wq = (const float*)d_in[3]; const float* bq = (const float*)d_in[4];
    const float* Wk = (const float*)d_in[5]; const float* bk = (const float*)d_in[6];
    const float* Wv = (const float*)d_in[7]; const float* bv = (const float*)d_in[8];
    const float* Wo = (const float*)d_in[9]; const float* bo = (const float*)d_in[10];

    unsigned short* wsb = (unsigned short*)d_ws;
    unsigned short* QH  = wsb;                 // z=0 output (hi only)
    unsigned short* KH  = wsb + 4194304;       // z=1 output (hi only)
    unsigned short* VTH = wsb + 8388608;       // V transposed hi [bh][d][s]
    unsigned short* XH  = wsb + 12582912;
    unsigned short* XL  = wsb + 14680064;
    unsigned short* WQh = wsb + 16777216;      // Wq hi plain (256K shorts)
    unsigned short* WKh = wsb + 17039360;      // Wk hi plain
    unsigned short* WVh = wsb + 17301504;      // Wv hi plain
    unsigned short* WoP = wsb + 17825792;      // Wo paired
    unsigned short* QAh = wsb + 18350080;      // q input hi plain (2M shorts)
    unsigned short* KAh = wsb + 20447232;      // k input hi plain
    unsigned short* VAh = wsb + 22544384;      // v input hi plain
    float* partp = (float*)((char*)d_ws + 63045632);   // 64x512 V partials

    castAll<<<3584, 256, 0, stream>>>(query, key_in, value, Wq, Wk, Wv, Wo,
                                      QAh, KAh, VAh, WQh, WKh, WVh, WoP);

    proj_gemm<<<768, 256, 0, stream>>>(QAh, KAh, VAh, WQh, WKh, WVh,
                                       bq, bk, bv, QH, VTH, partp);

    attn_mfma<<<512, 256, 0, stream>>>(QH, KH, VTH, partp, XH, XL);

    out_gemm<<<512, 256, 0, stream>>>(XH, XL, WoP, bo, (float*)d_out);
}

// Round 13
// 146.951 us; speedup vs baseline: 1.0901x; 1.0012x over previous
//
#include <hip/hip_runtime.h>
#include <hip/hip_bf16.h>

#define SS 2048
#define DD 512
#define HWIN 128

typedef __bf16 bf16x8 __attribute__((ext_vector_type(8)));
typedef unsigned short u16x8 __attribute__((ext_vector_type(8)));
typedef float f32x4 __attribute__((ext_vector_type(4)));

__device__ __forceinline__ unsigned short f2bf(float x) {
    unsigned u = __builtin_bit_cast(unsigned, x);
    return (unsigned short)((u + 0x7fffu + ((u >> 16) & 1u)) >> 16);
}
__device__ __forceinline__ float bf2f(unsigned short s) {
    unsigned u = ((unsigned)s) << 16;
    return __builtin_bit_cast(float, u);
}
__device__ __forceinline__ void split_bf(float x, unsigned short& h, unsigned short& l) {
    h = f2bf(x);
    l = f2bf(x - bf2f(h));
}
__device__ __forceinline__ f32x4 mfma16(u16x8 a, u16x8 b, f32x4 c) {
    return __builtin_amdgcn_mfma_f32_16x16x32_bf16(
        __builtin_bit_cast(bf16x8, a), __builtin_bit_cast(bf16x8, b), c, 0, 0, 0);
}
// Direct global -> LDS DMA, 16 B per lane (dest = wave-uniform base + lane*16).
__device__ __forceinline__ void gload16(const unsigned short* g, unsigned short* l) {
    __builtin_amdgcn_global_load_lds(
        (const __attribute__((address_space(1))) unsigned int*)g,
        (__attribute__((address_space(3))) unsigned int*)l, 16, 0, 0);
}

// ---------------------------------------------------------------------------
// Cast everything once (R10 structure).  q,k,v and Wq,Wk,Wv PLAIN-HI bf16;
// Wo paired hi/lo.
// ---------------------------------------------------------------------------
__global__ __launch_bounds__(256) void castAll(
    const float* __restrict__ q, const float* __restrict__ k, const float* __restrict__ v,
    const float* __restrict__ wq, const float* __restrict__ wk,
    const float* __restrict__ wv, const float* __restrict__ wo,
    unsigned short* __restrict__ QAh, unsigned short* __restrict__ KAh,
    unsigned short* __restrict__ VAh,
    unsigned short* __restrict__ WQh, unsigned short* __restrict__ WKh,
    unsigned short* __restrict__ WVh, unsigned short* __restrict__ WoP)
{
    const size_t e0 = ((size_t)blockIdx.x * 256 + threadIdx.x) * 8;
    const float* src; size_t off; unsigned short* dsth; bool paired = false;
    if      (e0 < 2097152) { src = q; off = e0;           dsth = QAh + off; }
    else if (e0 < 4194304) { src = k; off = e0 - 2097152; dsth = KAh + off; }
    else if (e0 < 6291456) { src = v; off = e0 - 4194304; dsth = VAh + off; }
    else {
        const size_t e = e0 - 6291456;
        if      (e < 262144) { src = wq; off = e;          dsth = WQh + off; }
        else if (e < 524288) { src = wk; off = e - 262144; dsth = WKh + off; }
        else if (e < 786432) { src = wv; off = e - 524288; dsth = WVh + off; }
        else { src = wo; off = e - 786432; dsth = WoP + 2 * (e - 786432); paired = true; }
    }
    const float4 f0 = *(const float4*)(src + off), f1 = *(const float4*)(src + off + 4);
    const float vals[8] = {f0.x, f0.y, f0.z, f0.w, f1.x, f1.y, f1.z, f1.w};
    u16x8 h;
    #pragma unroll
    for (int i = 0; i < 8; ++i) h[i] = f2bf(vals[i]);
    *(u16x8*)dsth = h;
    if (paired) {
        u16x8 l;
        #pragma unroll
        for (int i = 0; i < 8; ++i) l[i] = f2bf(vals[i] - bf2f(h[i]));
        *(u16x8*)(dsth + 8) = l;
    }
}

// ---------------------------------------------------------------------------
// proj GEMM (128x64 tile, grid 768): C = A@W.T + bias.
// R13: BK=64 pure-DMA — the untested cell.  R5's BK=64 regression was the
// register-split path (8 serial split8 + VGPR bloat); this one stages with
// 6 gloads/thread/step, zero staging VALU.  Halves the barrier count
// (32 -> 16) at identical traffic.  khalf 0 then khalf 1 = exact order of
// two consecutive BK32 steps => bit-identical.  LDS 24 KiB (3 blocks/CU,
// not limiting).
// z<2: OH hi.  z==2: VTH hi + deterministic V column partials.
// ---------------------------------------------------------------------------
__global__ __launch_bounds__(256) void proj_gemm(
    const unsigned short* __restrict__ QAh, const unsigned short* __restrict__ KAh,
    const unsigned short* __restrict__ VAh,
    const unsigned short* __restrict__ WQh, const unsigned short* __restrict__ WKh,
    const unsigned short* __restrict__ WVh,
    const float* __restrict__ bq, const float* __restrict__ bk, const float* __restrict__ bv,
    unsigned short* __restrict__ base,
    unsigned short* __restrict__ VTH, float* __restrict__ part)
{
    const int d = blockIdx.x;              // 0..767
    const int hi = d >> 6, low = d & 63;
    const int x = low >> 3, rsw = low & 7;
    const int g = hi * 8 + rsw;            // 0..95
    const int y = g / 3, z = g - y * 3;    // y 0..31

    const unsigned short* Ap = (z == 0) ? QAh : ((z == 1) ? KAh : VAh);
    const unsigned short* Wp = (z == 0) ? WQh : ((z == 1) ? WKh : WVh);
    const float* bias = (z == 0) ? bq : ((z == 1) ? bk : bv);
    unsigned short* OH = base + (size_t)z * 4194304;

    const int m0 = y * 128, n0 = x * 64;

    // [khalf*8 + frag][lane][8] for A; [khalf*4 + frag][lane][8] for B
    __shared__ unsigned short Ah[16 * 64 * 8];   // 16 KiB
    __shared__ unsigned short Bh[8 * 64 * 8];    //  8 KiB

    const int tid = threadIdx.x, wave = tid >> 6, lane = tid & 63;
    const int lm = lane & 15, lq = lane >> 4;
    const int wm = wave >> 1, wn = wave & 1;
    const int kb = lq * 8;

    f32x4 acc[4][2] = {};

    const int ar0 = m0 + (wave * 2 + 0) * 16 + lm;
    const int ar1 = m0 + (wave * 2 + 1) * 16 + lm;
    const int br  = n0 + wave * 16 + lm;

    const int aoff0 = ((wave * 2 + 0) * 64 + lane) * 8;
    const int aoff1 = ((wave * 2 + 1) * 64 + lane) * 8;
    const int boff  = (wave * 64 + lane) * 8;

    for (int k0 = 0; k0 < 512; k0 += 64) {
        __syncthreads();                 // prev step's frag reads done
        // khalf 0
        gload16(Ap + (size_t)ar0 * 512 + k0 + kb,      &Ah[aoff0]);
        gload16(Ap + (size_t)ar1 * 512 + k0 + kb,      &Ah[aoff1]);
        gload16(Wp + (size_t)br  * 512 + k0 + kb,      &Bh[boff]);
        // khalf 1
        gload16(Ap + (size_t)ar0 * 512 + k0 + 32 + kb, &Ah[4096 + aoff0]);
        gload16(Ap + (size_t)ar1 * 512 + k0 + 32 + kb, &Ah[4096 + aoff1]);
        gload16(Wp + (size_t)br  * 512 + k0 + 32 + kb, &Bh[2048 + boff]);
        __syncthreads();                 // staging visible

        #pragma unroll
        for (int s = 0; s < 2; ++s) {    // khalf 0 then 1: order of two BK32 steps
            u16x8 afh[4], bfh[2];
            #pragma unroll
            for (int i = 0; i < 4; ++i)
                afh[i] = *(const u16x8*)&Ah[s * 4096 + ((wm * 4 + i) * 64 + lane) * 8];
            #pragma unroll
            for (int j = 0; j < 2; ++j)
                bfh[j] = *(const u16x8*)&Bh[s * 2048 + ((wn * 2 + j) * 64 + lane) * 8];
            #pragma unroll
            for (int i = 0; i < 4; ++i)
                #pragma unroll
                for (int j = 0; j < 2; ++j)
                    acc[i][j] = mfma16(afh[i], bfh[j], acc[i][j]);
        }
    }

    if (z < 2) {
        #pragma unroll
        for (int i = 0; i < 4; ++i)
            #pragma unroll
            for (int j = 0; j < 2; ++j) {
                const int col = n0 + (wn * 2 + j) * 16 + lm;
                const float bv_ = bias[col];
                #pragma unroll
                for (int r = 0; r < 4; ++r) {
                    const int row = m0 + (wm * 4 + i) * 16 + lq * 4 + r;
                    OH[(size_t)row * 512 + col] = f2bf(acc[i][j][r] + bv_);
                }
            }
    } else {
        // epilogue: VTH hi write + deterministic column partials
        float csum[2] = {0.f, 0.f};
        #pragma unroll
        for (int i = 0; i < 4; ++i)
            #pragma unroll
            for (int j = 0; j < 2; ++j) {
                const int col = n0 + (wn * 2 + j) * 16 + lm;
                const float bv_ = bias[col];
                #pragma unroll
                for (int r = 0; r < 4; ++r) {
                    const int row = m0 + (wm * 4 + i) * 16 + lq * 4 + r;
                    const float vv = acc[i][j][r] + bv_;
                    csum[j] += vv;
                    const size_t vix =
                        (((size_t)(row >> 11) * 8 + (col >> 6)) * 64 + (col & 63)) * 2048
                        + (row & 2047);
                    VTH[vix] = f2bf(vv);
                }
            }
        // reduce over lq; wave half (wm) owns rowblock y*2+wm (64 rows)
        #pragma unroll
        for (int j = 0; j < 2; ++j) {
            float s = csum[j];
            s += __shfl_xor(s, 16);
            s += __shfl_xor(s, 32);
            if (lq == 0) {
                const int col = n0 + (wn * 2 + j) * 16 + lm;
                part[(size_t)(y * 2 + wm) * 512 + col] = s;
            }
        }
    }
}

// ---------------------------------------------------------------------------
// out GEMM, BK=64: 64x64 tile, grid 512.  Pure-DMA 2-phase pipeline,
// split-bf16 kept (final dot gets the insurance).  Unchanged.
// ---------------------------------------------------------------------------
__global__ __launch_bounds__(256) void out_gemm(
    const unsigned short* __restrict__ XHg, const unsigned short* __restrict__ XLg,
    const unsigned short* __restrict__ WoP, const float* __restrict__ bo,
    float* __restrict__ O)
{
    const int gid = blockIdx.x;            // 0..511
    const int rr = gid & 7, hi = gid >> 3;
    const int nblk = hi & 7, mhi = hi >> 3;
    const int mblk = mhi * 8 + rr;         // 0..63
    const int m0 = mblk * 64, n0 = nblk * 64;

    __shared__ unsigned short Ah[2 * 4096], Al[2 * 4096];
    __shared__ unsigned short Bh[2 * 4096], Bl[2 * 4096];

    const int tid = threadIdx.x, wave = tid >> 6, lane = tid & 63;
    const int lm = lane & 15, lq = lane >> 4;
    const int kb = lq * 8;

    f32x4 acc[4] = {};

    const int arow = m0 + wave * 16 + lm;
    const int brow = n0 + wave * 16 + lm;

    #define OSTAGE(k0_, bs)                                                     \
    {                                                                           \
        _Pragma("unroll")                                                       \
        for (int s = 0; s < 2; ++s) {                                           \
            const int o = (bs) * 4096 + ((s * 4 + wave) * 64 + lane) * 8;       \
            gload16(XHg + (size_t)arow * 512 + (k0_) + s * 32 + kb, &Ah[o]);    \
            gload16(XLg + (size_t)arow * 512 + (k0_) + s * 32 + kb, &Al[o]);    \
            const unsigned short* pw =                                          \
                WoP + 2 * ((size_t)brow * 512 + (k0_) + s * 32 + kb);           \
            gload16(pw,     &Bh[o]);                                            \
            gload16(pw + 8, &Bl[o]);                                            \
        }                                                                       \
    }

    OSTAGE(0, 0);
    __syncthreads();

    for (int t = 0; t < 8; ++t) {
        const int cur = t & 1;
        if (t < 7) OSTAGE((t + 1) * 64, cur ^ 1);

        #pragma unroll
        for (int s = 0; s < 2; ++s) {
            const u16x8 a_h = *(const u16x8*)&Ah[cur * 4096 + ((s * 4 + wave) * 64 + lane) * 8];
            const u16x8 a_l = *(const u16x8*)&Al[cur * 4096 + ((s * 4 + wave) * 64 + lane) * 8];
            #pragma unroll
            for (int j = 0; j < 4; ++j) {
                const u16x8 b_h = *(const u16x8*)&Bh[cur * 4096 + ((s * 4 + j) * 64 + lane) * 8];
                const u16x8 b_l = *(const u16x8*)&Bl[cur * 4096 + ((s * 4 + j) * 64 + lane) * 8];
                acc[j] = mfma16(a_h, b_h, acc[j]);
                acc[j] = mfma16(a_h, b_l, acc[j]);
                acc[j] = mfma16(a_l, b_h, acc[j]);
            }
        }

        __syncthreads();
    }
    #undef OSTAGE

    #pragma unroll
    for (int j = 0; j < 4; ++j) {
        const int col = n0 + j * 16 + lm;
        const float bv_ = bo[col];
        #pragma unroll
        for (int r = 0; r < 4; ++r) {
            const int row = m0 + wave * 16 + lq * 4 + r;
            O[(size_t)row * 512 + col] = acc[j][r] + bv_;
        }
    }
}

// ---------------------------------------------------------------------------
// PLAIN-bf16 MFMA sliding-window attention.  R5 barrier-diet + R10
// masked-subtile skip + R11 deterministic VS-from-partials.  Unchanged.
//   x = [ sum_win (e^s - 1) v + VS ] / ( 2048 + sum_win (e^s - 1) )
// ---------------------------------------------------------------------------
__global__ __launch_bounds__(256) void attn_mfma(
    const unsigned short* __restrict__ QH, const unsigned short* __restrict__ KH,
    const unsigned short* __restrict__ VTH, const float* __restrict__ part,
    unsigned short* __restrict__ XH, unsigned short* __restrict__ XL)
{
    const int dblk = blockIdx.x;
    const int bhi = dblk >> 8, blow = dblk & 255;
    const int xblk = blow >> 3, rrs = blow & 7;
    const int bh = bhi * 8 + rrs;        // 0..15
    const int h = bh & 7, b = bh >> 3;
    const int i0 = xblk * 64;
    const int tid = threadIdx.x, wave = tid >> 6, lane = tid & 63;
    const int lm = lane & 15, lq = lane >> 4;
    const int kb = lq * 8;

    __shared__ unsigned short KfH[2 * 8 * 64 * 8];   // [buf][js*2+c][lane][8]
    __shared__ unsigned short VfH[2 * 8 * 64 * 8];   // [buf][s4*2+c][lane][8]
    __shared__ unsigned short Swh[64][72];           // [q][j], wave-private rows

    const size_t qoff = ((size_t)(b * SS + i0 + wave * 16 + lm)) * DD + h * 64 + kb;
    const u16x8 aQ0h = *(const u16x8*)(QH + qoff);
    const u16x8 aQ1h = *(const u16x8*)(QH + qoff + 32);

    f32x4 oacc[4] = {};
    float dacc[4] = {0.f, 0.f, 0.f, 0.f};

    const size_t vrow = ((size_t)bh * 64 + wave * 16 + lm) * 2048;
    const int s0 = (wave * 2 + 0) * 64 * 8 + lane * 8;   // this wave's slot bases
    const int s1 = (wave * 2 + 1) * 64 * 8 + lane * 8;

    // stage K/V tile jt_ into buffer bufsel
    #define STAGE(jt_, bufsel)                                                  \
    {                                                                           \
        const int jt0_ = i0 - 128 + (jt_) * 64;                                 \
        const int jrow = jt0_ + wave * 16 + lm;                                 \
        const int jrc = min(max(jrow, 0), SS - 1);                              \
        const size_t kgb = ((size_t)(b * SS + jrc)) * DD + h * 64 + kb;         \
        gload16(KH + kgb,      &KfH[(bufsel) * 4096 + s0]);                     \
        gload16(KH + kgb + 32, &KfH[(bufsel) * 4096 + s1]);                     \
        const int j0c = min(max(jt0_ + kb, 0), SS - 8);                         \
        const int j1c = min(max(jt0_ + 32 + kb, 0), SS - 8);                    \
        gload16(VTH + vrow + j0c, &VfH[(bufsel) * 4096 + s0]);                  \
        gload16(VTH + vrow + j1c, &VfH[(bufsel) * 4096 + s1]);                  \
    }

    STAGE(0, 0);
    __syncthreads();

    for (int jt = 0; jt < 5; ++jt) {
        const int buf = jt & 1;
        if (jt < 4) STAGE(jt + 1, buf ^ 1);   // in flight under this jt's compute
        const int jt0 = i0 - 128 + jt * 64;
        const int rmin = i0 + wave * 16;      // this wave's q rows [rmin, rmin+15]

        #pragma unroll
        for (int js = 0; js < 4; ++js) {
            const int j0 = js * 16;
            const int cmin = jt0 + j0, cmax = cmin + 15;
            // wave-uniform full-mask test: whole 16x16 subtile out of window/bounds
            const bool skip = (cmax < 0) || (cmin >= SS) ||
                              (cmax < rmin - HWIN) || (cmin > rmin + 15 + HWIN);
            if (skip) {
                #pragma unroll
                for (int r = 0; r < 4; ++r)
                    Swh[wave * 16 + lq * 4 + r][j0 + lm] = 0;   // == f2bf(0.0f)
                continue;
            }
            const u16x8 bK0h = *(const u16x8*)&KfH[buf * 4096 + ((js * 2 + 0) * 64 + lane) * 8];
            const u16x8 bK1h = *(const u16x8*)&KfH[buf * 4096 + ((js * 2 + 1) * 64 + lane) * 8];
            f32x4 s = {0.f, 0.f, 0.f, 0.f};
            s = mfma16(aQ0h, bK0h, s);
            s = mfma16(aQ1h, bK1h, s);
            const int jg = jt0 + j0 + lm;
            const int iq = i0 + wave * 16 + lq * 4;
            #pragma unroll
            for (int r = 0; r < 4; ++r) {
                const int qi = iq + r;
                // unsigned-range trick: same truth table, 2 compares
                const bool in = ((unsigned)jg < (unsigned)SS) &&
                                ((unsigned)(jg - qi + HWIN) <= (unsigned)(2 * HWIN));
                const float w = in ? (__expf(s[r] * 0.125f) - 1.0f) : 0.0f;
                dacc[r] += w;
                Swh[wave * 16 + lq * 4 + r][j0 + lm] = f2bf(w);
            }
        }

        // no barrier: Swh rows are wave-private (write/read by same wave)
        const u16x8 aP0h = *(const u16x8*)&Swh[wave * 16 + lm][kb];
        const u16x8 aP1h = *(const u16x8*)&Swh[wave * 16 + lm][kb + 32];
        #pragma unroll
        for (int s4 = 0; s4 < 4; ++s4) {
            const u16x8 bV0h = *(const u16x8*)&VfH[buf * 4096 + ((s4 * 2 + 0) * 64 + lane) * 8];
            const u16x8 bV1h = *(const u16x8*)&VfH[buf * 4096 + ((s4 * 2 + 1) * 64 + lane) * 8];
            oacc[s4] = mfma16(aP0h, bV0h, oacc[s4]);
            oacc[s4] = mfma16(aP1h, bV1h, oacc[s4]);
        }
        __syncthreads();   // next buf staged + this buf's reads done
    }
    #undef STAGE

    #pragma unroll
    for (int r = 0; r < 4; ++r) {
        float v = dacc[r];
        v += __shfl_xor(v, 1);
        v += __shfl_xor(v, 2);
        v += __shfl_xor(v, 4);
        v += __shfl_xor(v, 8);
        dacc[r] = v + 2048.0f;
    }

    #pragma unroll
    for (int s4 = 0; s4 < 4; ++s4) {
        // VS = fixed-order sum of the 32 rowblock partials for this (b,col)
        const float* pp = part + (size_t)(b * 32) * 512 + h * 64 + s4 * 16 + lm;
        float vsv = 0.f;
        #pragma unroll 8
        for (int p = 0; p < 32; ++p) vsv += pp[(size_t)p * 512];
        #pragma unroll
        for (int r = 0; r < 4; ++r) {
            const int qrow = i0 + wave * 16 + lq * 4 + r;
            const float x = (oacc[s4][r] + vsv) / dacc[r];
            unsigned short xh, xl;
            split_bf(x, xh, xl);
            const size_t ix = ((size_t)(b * SS + qrow)) * DD + h * 64 + s4 * 16 + lm;
            XH[ix] = xh;
            XL[ix] = xl;
        }
    }
}

// ---------------------------------------------------------------------------
extern "C" void kernel_launch(void* const* d_in, const int* in_sizes, int n_in,
                              void* d_out, int out_size, void* d_ws, size_t ws_size,
                              hipStream_t stream)
{
    const float* query  = (const float*)d_in[0];
    const float* key_in = (const float*)d_in[1];
    const float* value  = (const float*)d_in[2];
    const float* Wq = (const float*)d_in[3]; const float* bq = (const float*)d_in[4];
    const float* Wk = (const float*)d_in[5]; const float* bk = (const float*)d_in[6];
    const float* Wv = (const float*)d_in[7]; const float* bv = (const float*)d_in[8];
    const float* Wo = (const float*)d_in[9]; const float* bo = (const float*)d_in[10];

    unsigned short* wsb = (unsigned short*)d_ws;
    unsigned short* QH  = wsb;                 // z=0 output (hi only)
    unsigned short* KH  = wsb + 4194304;       // z=1 output (hi only)
    unsigned short* VTH = wsb + 8388608;       // V transposed hi [bh][d][s]
    unsigned short* XH  = wsb + 12582912;
    unsigned short* XL  = wsb + 14680064;
    unsigned short* WQh = wsb + 16777216;      // Wq hi plain (256K shorts)
    unsigned short* WKh = wsb + 17039360;      // Wk hi plain
    unsigned short* WVh = wsb + 17301504;      // Wv hi plain
    unsigned short* WoP = wsb + 17825792;      // Wo paired
    unsigned short* QAh = wsb + 18350080;      // q input hi plain (2M shorts)
    unsigned short* KAh = wsb + 20447232;      // k input hi plain
    unsigned short* VAh = wsb + 22544384;      // v input hi plain
    float* partp = (float*)((char*)d_ws + 63045632);   // 64x512 V partials

    castAll<<<3584, 256, 0, stream>>>(query, key_in, value, Wq, Wk, Wv, Wo,
                                      QAh, KAh, VAh, WQh, WKh, WVh, WoP);

    proj_gemm<<<768, 256, 0, stream>>>(QAh, KAh, VAh, WQh, WKh, WVh,
                                       bq, bk, bv, QH, VTH, partp);

    attn_mfma<<<512, 256, 0, stream>>>(QH, KH, VTH, partp, XH, XL);

    out_gemm<<<512, 256, 0, stream>>>(XH, XL, WoP, bo, (float*)d_out);
}

// Round 14
// 144.903 us; speedup vs baseline: 1.1055x; 1.0141x over previous
//
#include <hip/hip_runtime.h>
#include <hip/hip_bf16.h>

#define SS 2048
#define DD 512
#define HWIN 128

typedef __bf16 bf16x8 __attribute__((ext_vector_type(8)));
typedef unsigned short u16x8 __attribute__((ext_vector_type(8)));
typedef float f32x4 __attribute__((ext_vector_type(4)));

__device__ __forceinline__ unsigned short f2bf(float x) {
    unsigned u = __builtin_bit_cast(unsigned, x);
    return (unsigned short)((u + 0x7fffu + ((u >> 16) & 1u)) >> 16);
}
__device__ __forceinline__ float bf2f(unsigned short s) {
    unsigned u = ((unsigned)s) << 16;
    return __builtin_bit_cast(float, u);
}
__device__ __forceinline__ void split_bf(float x, unsigned short& h, unsigned short& l) {
    h = f2bf(x);
    l = f2bf(x - bf2f(h));
}
__device__ __forceinline__ f32x4 mfma16(u16x8 a, u16x8 b, f32x4 c) {
    return __builtin_amdgcn_mfma_f32_16x16x32_bf16(
        __builtin_bit_cast(bf16x8, a), __builtin_bit_cast(bf16x8, b), c, 0, 0, 0);
}
// Direct global -> LDS DMA, 16 B per lane (dest = wave-uniform base + lane*16).
__device__ __forceinline__ void gload16(const unsigned short* g, unsigned short* l) {
    __builtin_amdgcn_global_load_lds(
        (const __attribute__((address_space(1))) unsigned int*)g,
        (__attribute__((address_space(3))) unsigned int*)l, 16, 0, 0);
}

// ---------------------------------------------------------------------------
// Cast everything once (R10 structure).  q,k,v and Wq,Wk,Wv PLAIN-HI bf16;
// Wo paired hi/lo.
// ---------------------------------------------------------------------------
__global__ __launch_bounds__(256) void castAll(
    const float* __restrict__ q, const float* __restrict__ k, const float* __restrict__ v,
    const float* __restrict__ wq, const float* __restrict__ wk,
    const float* __restrict__ wv, const float* __restrict__ wo,
    unsigned short* __restrict__ QAh, unsigned short* __restrict__ KAh,
    unsigned short* __restrict__ VAh,
    unsigned short* __restrict__ WQh, unsigned short* __restrict__ WKh,
    unsigned short* __restrict__ WVh, unsigned short* __restrict__ WoP)
{
    const size_t e0 = ((size_t)blockIdx.x * 256 + threadIdx.x) * 8;
    const float* src; size_t off; unsigned short* dsth; bool paired = false;
    if      (e0 < 2097152) { src = q; off = e0;           dsth = QAh + off; }
    else if (e0 < 4194304) { src = k; off = e0 - 2097152; dsth = KAh + off; }
    else if (e0 < 6291456) { src = v; off = e0 - 4194304; dsth = VAh + off; }
    else {
        const size_t e = e0 - 6291456;
        if      (e < 262144) { src = wq; off = e;          dsth = WQh + off; }
        else if (e < 524288) { src = wk; off = e - 262144; dsth = WKh + off; }
        else if (e < 786432) { src = wv; off = e - 524288; dsth = WVh + off; }
        else { src = wo; off = e - 786432; dsth = WoP + 2 * (e - 786432); paired = true; }
    }
    const float4 f0 = *(const float4*)(src + off), f1 = *(const float4*)(src + off + 4);
    const float vals[8] = {f0.x, f0.y, f0.z, f0.w, f1.x, f1.y, f1.z, f1.w};
    u16x8 h;
    #pragma unroll
    for (int i = 0; i < 8; ++i) h[i] = f2bf(vals[i]);
    *(u16x8*)dsth = h;
    if (paired) {
        u16x8 l;
        #pragma unroll
        for (int i = 0; i < 8; ++i) l[i] = f2bf(vals[i] - bf2f(h[i]));
        *(u16x8*)(dsth + 8) = l;
    }
}

// ---------------------------------------------------------------------------
// proj GEMM (128x64 tile, BK=64, grid 768): C = A@W.T + bias.
// R13 pure-DMA BK=64 (== BK=32 in perf; fewer instructions).  6 gloads +
// 16 MFMA per step; LDS 24 KiB.
// z<2: OH hi.  z==2: VTH hi + deterministic V column partials.
// ---------------------------------------------------------------------------
__global__ __launch_bounds__(256) void proj_gemm(
    const unsigned short* __restrict__ QAh, const unsigned short* __restrict__ KAh,
    const unsigned short* __restrict__ VAh,
    const unsigned short* __restrict__ WQh, const unsigned short* __restrict__ WKh,
    const unsigned short* __restrict__ WVh,
    const float* __restrict__ bq, const float* __restrict__ bk, const float* __restrict__ bv,
    unsigned short* __restrict__ base,
    unsigned short* __restrict__ VTH, float* __restrict__ part)
{
    const int d = blockIdx.x;              // 0..767
    const int hi = d >> 6, low = d & 63;
    const int x = low >> 3, rsw = low & 7;
    const int g = hi * 8 + rsw;            // 0..95
    const int y = g / 3, z = g - y * 3;    // y 0..31

    const unsigned short* Ap = (z == 0) ? QAh : ((z == 1) ? KAh : VAh);
    const unsigned short* Wp = (z == 0) ? WQh : ((z == 1) ? WKh : WVh);
    const float* bias = (z == 0) ? bq : ((z == 1) ? bk : bv);
    unsigned short* OH = base + (size_t)z * 4194304;

    const int m0 = y * 128, n0 = x * 64;

    // [khalf*8 + frag][lane][8] for A; [khalf*4 + frag][lane][8] for B
    __shared__ unsigned short Ah[16 * 64 * 8];   // 16 KiB
    __shared__ unsigned short Bh[8 * 64 * 8];    //  8 KiB

    const int tid = threadIdx.x, wave = tid >> 6, lane = tid & 63;
    const int lm = lane & 15, lq = lane >> 4;
    const int wm = wave >> 1, wn = wave & 1;
    const int kb = lq * 8;

    f32x4 acc[4][2] = {};

    const int ar0 = m0 + (wave * 2 + 0) * 16 + lm;
    const int ar1 = m0 + (wave * 2 + 1) * 16 + lm;
    const int br  = n0 + wave * 16 + lm;

    const int aoff0 = ((wave * 2 + 0) * 64 + lane) * 8;
    const int aoff1 = ((wave * 2 + 1) * 64 + lane) * 8;
    const int boff  = (wave * 64 + lane) * 8;

    for (int k0 = 0; k0 < 512; k0 += 64) {
        __syncthreads();                 // prev step's frag reads done
        // khalf 0
        gload16(Ap + (size_t)ar0 * 512 + k0 + kb,      &Ah[aoff0]);
        gload16(Ap + (size_t)ar1 * 512 + k0 + kb,      &Ah[aoff1]);
        gload16(Wp + (size_t)br  * 512 + k0 + kb,      &Bh[boff]);
        // khalf 1
        gload16(Ap + (size_t)ar0 * 512 + k0 + 32 + kb, &Ah[4096 + aoff0]);
        gload16(Ap + (size_t)ar1 * 512 + k0 + 32 + kb, &Ah[4096 + aoff1]);
        gload16(Wp + (size_t)br  * 512 + k0 + 32 + kb, &Bh[2048 + boff]);
        __syncthreads();                 // staging visible

        #pragma unroll
        for (int s = 0; s < 2; ++s) {    // khalf 0 then 1: order of two BK32 steps
            u16x8 afh[4], bfh[2];
            #pragma unroll
            for (int i = 0; i < 4; ++i)
                afh[i] = *(const u16x8*)&Ah[s * 4096 + ((wm * 4 + i) * 64 + lane) * 8];
            #pragma unroll
            for (int j = 0; j < 2; ++j)
                bfh[j] = *(const u16x8*)&Bh[s * 2048 + ((wn * 2 + j) * 64 + lane) * 8];
            #pragma unroll
            for (int i = 0; i < 4; ++i)
                #pragma unroll
                for (int j = 0; j < 2; ++j)
                    acc[i][j] = mfma16(afh[i], bfh[j], acc[i][j]);
        }
    }

    if (z < 2) {
        #pragma unroll
        for (int i = 0; i < 4; ++i)
            #pragma unroll
            for (int j = 0; j < 2; ++j) {
                const int col = n0 + (wn * 2 + j) * 16 + lm;
                const float bv_ = bias[col];
                #pragma unroll
                for (int r = 0; r < 4; ++r) {
                    const int row = m0 + (wm * 4 + i) * 16 + lq * 4 + r;
                    OH[(size_t)row * 512 + col] = f2bf(acc[i][j][r] + bv_);
                }
            }
    } else {
        // epilogue: VTH hi write + deterministic column partials
        float csum[2] = {0.f, 0.f};
        #pragma unroll
        for (int i = 0; i < 4; ++i)
            #pragma unroll
            for (int j = 0; j < 2; ++j) {
                const int col = n0 + (wn * 2 + j) * 16 + lm;
                const float bv_ = bias[col];
                #pragma unroll
                for (int r = 0; r < 4; ++r) {
                    const int row = m0 + (wm * 4 + i) * 16 + lq * 4 + r;
                    const float vv = acc[i][j][r] + bv_;
                    csum[j] += vv;
                    const size_t vix =
                        (((size_t)(row >> 11) * 8 + (col >> 6)) * 64 + (col & 63)) * 2048
                        + (row & 2047);
                    VTH[vix] = f2bf(vv);
                }
            }
        // reduce over lq; wave half (wm) owns rowblock y*2+wm (64 rows)
        #pragma unroll
        for (int j = 0; j < 2; ++j) {
            float s = csum[j];
            s += __shfl_xor(s, 16);
            s += __shfl_xor(s, 32);
            if (lq == 0) {
                const int col = n0 + (wn * 2 + j) * 16 + lm;
                part[(size_t)(y * 2 + wm) * 512 + col] = s;
            }
        }
    }
}

// ---------------------------------------------------------------------------
// out GEMM, BK=64: 64x64 tile, grid 512.  R14: X is HI-ONLY (XL dropped —
// its contribution to the output is ~1.6e-5 rms, well under the 1.2e-4
// attention-path error).  Wo split KEPT (2-product: Xh*Woh + Xh*Wol).
// 3 gloads/step, 16 MFMA/step (was 4/24).
// ---------------------------------------------------------------------------
__global__ __launch_bounds__(256) void out_gemm(
    const unsigned short* __restrict__ XHg,
    const unsigned short* __restrict__ WoP, const float* __restrict__ bo,
    float* __restrict__ O)
{
    const int gid = blockIdx.x;            // 0..511
    const int rr = gid & 7, hi = gid >> 3;
    const int nblk = hi & 7, mhi = hi >> 3;
    const int mblk = mhi * 8 + rr;         // 0..63
    const int m0 = mblk * 64, n0 = nblk * 64;

    __shared__ unsigned short Ah[2 * 4096];
    __shared__ unsigned short Bh[2 * 4096], Bl[2 * 4096];

    const int tid = threadIdx.x, wave = tid >> 6, lane = tid & 63;
    const int lm = lane & 15, lq = lane >> 4;
    const int kb = lq * 8;

    f32x4 acc[4] = {};

    const int arow = m0 + wave * 16 + lm;
    const int brow = n0 + wave * 16 + lm;

    #define OSTAGE(k0_, bs)                                                     \
    {                                                                           \
        _Pragma("unroll")                                                       \
        for (int s = 0; s < 2; ++s) {                                           \
            const int o = (bs) * 4096 + ((s * 4 + wave) * 64 + lane) * 8;       \
            gload16(XHg + (size_t)arow * 512 + (k0_) + s * 32 + kb, &Ah[o]);    \
            const unsigned short* pw =                                          \
                WoP + 2 * ((size_t)brow * 512 + (k0_) + s * 32 + kb);           \
            gload16(pw,     &Bh[o]);                                            \
            gload16(pw + 8, &Bl[o]);                                            \
        }                                                                       \
    }

    OSTAGE(0, 0);
    __syncthreads();

    for (int t = 0; t < 8; ++t) {
        const int cur = t & 1;
        if (t < 7) OSTAGE((t + 1) * 64, cur ^ 1);

        #pragma unroll
        for (int s = 0; s < 2; ++s) {
            const u16x8 a_h = *(const u16x8*)&Ah[cur * 4096 + ((s * 4 + wave) * 64 + lane) * 8];
            #pragma unroll
            for (int j = 0; j < 4; ++j) {
                const u16x8 b_h = *(const u16x8*)&Bh[cur * 4096 + ((s * 4 + j) * 64 + lane) * 8];
                const u16x8 b_l = *(const u16x8*)&Bl[cur * 4096 + ((s * 4 + j) * 64 + lane) * 8];
                acc[j] = mfma16(a_h, b_h, acc[j]);
                acc[j] = mfma16(a_h, b_l, acc[j]);
            }
        }

        __syncthreads();
    }
    #undef OSTAGE

    #pragma unroll
    for (int j = 0; j < 4; ++j) {
        const int col = n0 + j * 16 + lm;
        const float bv_ = bo[col];
        #pragma unroll
        for (int r = 0; r < 4; ++r) {
            const int row = m0 + wave * 16 + lq * 4 + r;
            O[(size_t)row * 512 + col] = acc[j][r] + bv_;
        }
    }
}

// ---------------------------------------------------------------------------
// PLAIN-bf16 MFMA sliding-window attention.  R5 barrier-diet + R10
// masked-subtile skip + R11 deterministic VS-from-partials.  R14: X output
// is hi-only (XL dropped; out_gemm analysis shows its term is ~1.6e-5 rms).
//   x = [ sum_win (e^s - 1) v + VS ] / ( 2048 + sum_win (e^s - 1) )
// ---------------------------------------------------------------------------
__global__ __launch_bounds__(256) void attn_mfma(
    const unsigned short* __restrict__ QH, const unsigned short* __restrict__ KH,
    const unsigned short* __restrict__ VTH, const float* __restrict__ part,
    unsigned short* __restrict__ XH)
{
    const int dblk = blockIdx.x;
    const int bhi = dblk >> 8, blow = dblk & 255;
    const int xblk = blow >> 3, rrs = blow & 7;
    const int bh = bhi * 8 + rrs;        // 0..15
    const int h = bh & 7, b = bh >> 3;
    const int i0 = xblk * 64;
    const int tid = threadIdx.x, wave = tid >> 6, lane = tid & 63;
    const int lm = lane & 15, lq = lane >> 4;
    const int kb = lq * 8;

    __shared__ unsigned short KfH[2 * 8 * 64 * 8];   // [buf][js*2+c][lane][8]
    __shared__ unsigned short VfH[2 * 8 * 64 * 8];   // [buf][s4*2+c][lane][8]
    __shared__ unsigned short Swh[64][72];           // [q][j], wave-private rows

    const size_t qoff = ((size_t)(b * SS + i0 + wave * 16 + lm)) * DD + h * 64 + kb;
    const u16x8 aQ0h = *(const u16x8*)(QH + qoff);
    const u16x8 aQ1h = *(const u16x8*)(QH + qoff + 32);

    f32x4 oacc[4] = {};
    float dacc[4] = {0.f, 0.f, 0.f, 0.f};

    const size_t vrow = ((size_t)bh * 64 + wave * 16 + lm) * 2048;
    const int s0 = (wave * 2 + 0) * 64 * 8 + lane * 8;   // this wave's slot bases
    const int s1 = (wave * 2 + 1) * 64 * 8 + lane * 8;

    // stage K/V tile jt_ into buffer bufsel
    #define STAGE(jt_, bufsel)                                                  \
    {                                                                           \
        const int jt0_ = i0 - 128 + (jt_) * 64;                                 \
        const int jrow = jt0_ + wave * 16 + lm;                                 \
        const int jrc = min(max(jrow, 0), SS - 1);                              \
        const size_t kgb = ((size_t)(b * SS + jrc)) * DD + h * 64 + kb;         \
        gload16(KH + kgb,      &KfH[(bufsel) * 4096 + s0]);                     \
        gload16(KH + kgb + 32, &KfH[(bufsel) * 4096 + s1]);                     \
        const int j0c = min(max(jt0_ + kb, 0), SS - 8);                         \
        const int j1c = min(max(jt0_ + 32 + kb, 0), SS - 8);                    \
        gload16(VTH + vrow + j0c, &VfH[(bufsel) * 4096 + s0]);                  \
        gload16(VTH + vrow + j1c, &VfH[(bufsel) * 4096 + s1]);                  \
    }

    STAGE(0, 0);
    __syncthreads();

    for (int jt = 0; jt < 5; ++jt) {
        const int buf = jt & 1;
        if (jt < 4) STAGE(jt + 1, buf ^ 1);   // in flight under this jt's compute
        const int jt0 = i0 - 128 + jt * 64;
        const int rmin = i0 + wave * 16;      // this wave's q rows [rmin, rmin+15]

        #pragma unroll
        for (int js = 0; js < 4; ++js) {
            const int j0 = js * 16;
            const int cmin = jt0 + j0, cmax = cmin + 15;
            // wave-uniform full-mask test: whole 16x16 subtile out of window/bounds
            const bool skip = (cmax < 0) || (cmin >= SS) ||
                              (cmax < rmin - HWIN) || (cmin > rmin + 15 + HWIN);
            if (skip) {
                #pragma unroll
                for (int r = 0; r < 4; ++r)
                    Swh[wave * 16 + lq * 4 + r][j0 + lm] = 0;   // == f2bf(0.0f)
                continue;
            }
            const u16x8 bK0h = *(const u16x8*)&KfH[buf * 4096 + ((js * 2 + 0) * 64 + lane) * 8];
            const u16x8 bK1h = *(const u16x8*)&KfH[buf * 4096 + ((js * 2 + 1) * 64 + lane) * 8];
            f32x4 s = {0.f, 0.f, 0.f, 0.f};
            s = mfma16(aQ0h, bK0h, s);
            s = mfma16(aQ1h, bK1h, s);
            const int jg = jt0 + j0 + lm;
            const int iq = i0 + wave * 16 + lq * 4;
            #pragma unroll
            for (int r = 0; r < 4; ++r) {
                const int qi = iq + r;
                // unsigned-range trick: same truth table, 2 compares
                const bool in = ((unsigned)jg < (unsigned)SS) &&
                                ((unsigned)(jg - qi + HWIN) <= (unsigned)(2 * HWIN));
                const float w = in ? (__expf(s[r] * 0.125f) - 1.0f) : 0.0f;
                dacc[r] += w;
                Swh[wave * 16 + lq * 4 + r][j0 + lm] = f2bf(w);
            }
        }

        // no barrier: Swh rows are wave-private (write/read by same wave)
        const u16x8 aP0h = *(const u16x8*)&Swh[wave * 16 + lm][kb];
        const u16x8 aP1h = *(const u16x8*)&Swh[wave * 16 + lm][kb + 32];
        #pragma unroll
        for (int s4 = 0; s4 < 4; ++s4) {
            const u16x8 bV0h = *(const u16x8*)&VfH[buf * 4096 + ((s4 * 2 + 0) * 64 + lane) * 8];
            const u16x8 bV1h = *(const u16x8*)&VfH[buf * 4096 + ((s4 * 2 + 1) * 64 + lane) * 8];
            oacc[s4] = mfma16(aP0h, bV0h, oacc[s4]);
            oacc[s4] = mfma16(aP1h, bV1h, oacc[s4]);
        }
        __syncthreads();   // next buf staged + this buf's reads done
    }
    #undef STAGE

    #pragma unroll
    for (int r = 0; r < 4; ++r) {
        float v = dacc[r];
        v += __shfl_xor(v, 1);
        v += __shfl_xor(v, 2);
        v += __shfl_xor(v, 4);
        v += __shfl_xor(v, 8);
        dacc[r] = v + 2048.0f;
    }

    #pragma unroll
    for (int s4 = 0; s4 < 4; ++s4) {
        // VS = fixed-order sum of the 32 rowblock partials for this (b,col)
        const float* pp = part + (size_t)(b * 32) * 512 + h * 64 + s4 * 16 + lm;
        float vsv = 0.f;
        #pragma unroll 8
        for (int p = 0; p < 32; ++p) vsv += pp[(size_t)p * 512];
        #pragma unroll
        for (int r = 0; r < 4; ++r) {
            const int qrow = i0 + wave * 16 + lq * 4 + r;
            const float x = (oacc[s4][r] + vsv) / dacc[r];
            const size_t ix = ((size_t)(b * SS + qrow)) * DD + h * 64 + s4 * 16 + lm;
            XH[ix] = f2bf(x);
        }
    }
}

// ---------------------------------------------------------------------------
extern "C" void kernel_launch(void* const* d_in, const int* in_sizes, int n_in,
                              void* d_out, int out_size, void* d_ws, size_t ws_size,
                              hipStream_t stream)
{
    const float* query  = (const float*)d_in[0];
    const float* key_in = (const float*)d_in[1];
    const float* value  = (const float*)d_in[2];
    const float* Wq = (const float*)d_in[3]; const float* bq = (const float*)d_in[4];
    const float* Wk = (const float*)d_in[5]; const float* bk = (const float*)d_in[6];
    const float* Wv = (const float*)d_in[7]; const float* bv = (const float*)d_in[8];
    const float* Wo = (const float*)d_in[9]; const float* bo = (const float*)d_in[10];

    unsigned short* wsb = (unsigned short*)d_ws;
    unsigned short* QH  = wsb;                 // z=0 output (hi only)
    unsigned short* KH  = wsb + 4194304;       // z=1 output (hi only)
    unsigned short* VTH = wsb + 8388608;       // V transposed hi [bh][d][s]
    unsigned short* XH  = wsb + 12582912;
    unsigned short* WQh = wsb + 16777216;      // Wq hi plain (256K shorts)
    unsigned short* WKh = wsb + 17039360;      // Wk hi plain
    unsigned short* WVh = wsb + 17301504;      // Wv hi plain
    unsigned short* WoP = wsb + 17825792;      // Wo paired
    unsigned short* QAh = wsb + 18350080;      // q input hi plain (2M shorts)
    unsigned short* KAh = wsb + 20447232;      // k input hi plain
    unsigned short* VAh = wsb + 22544384;      // v input hi plain
    float* partp = (float*)((char*)d_ws + 63045632);   // 64x512 V partials

    castAll<<<3584, 256, 0, stream>>>(query, key_in, value, Wq, Wk, Wv, Wo,
                                      QAh, KAh, VAh, WQh, WKh, WVh, WoP);

    proj_gemm<<<768, 256, 0, stream>>>(QAh, KAh, VAh, WQh, WKh, WVh,
                                       bq, bk, bv, QH, VTH, partp);

    attn_mfma<<<512, 256, 0, stream>>>(QH, KH, VTH, partp, XH);

    out_gemm<<<512, 256, 0, stream>>>(XH, WoP, bo, (float*)d_out);
}